// Round 1
// baseline (380.917 us; speedup 1.0000x reference)
//
#include <hip/hip_runtime.h>
#include <math.h>

#define ROWLEN 4096
#define BLK 256

// strict ordering matching jax.lax.top_k tie-break: higher value wins,
// equal value -> lower index wins
__device__ __forceinline__ bool better(float v, int i, float w, int j) {
    return (v > w) || (v == w && i < j);
}

// insert (v,i) into sorted-descending triple (v0,i0)>(v1,i1)>(v2,i2)
__device__ __forceinline__ void ins3(float v, int i,
                                     float& v0, int& i0,
                                     float& v1, int& i1,
                                     float& v2, int& i2) {
    if (better(v, i, v2, i2)) {
        if (better(v, i, v1, i1)) {
            v2 = v1; i2 = i1;
            if (better(v, i, v0, i0)) {
                v1 = v0; i1 = i0; v0 = v; i0 = i;
            } else { v1 = v; i1 = i; }
        } else { v2 = v; i2 = i; }
    }
}

// merge sorted triple b into sorted triple a (keep top 3 of the 6)
__device__ __forceinline__ void merge3(float& a0, int& x0, float& a1, int& x1, float& a2, int& x2,
                                       float b0, int y0, float b1, int y1, float b2, int y2) {
    float o0, o1, o2; int p0, p1, p2;
    if (better(a0, x0, b0, y0)) {
        o0 = a0; p0 = x0;
        if (better(a1, x1, b0, y0)) {
            o1 = a1; p1 = x1;
            if (better(a2, x2, b0, y0)) { o2 = a2; p2 = x2; } else { o2 = b0; p2 = y0; }
        } else {
            o1 = b0; p1 = y0;
            if (better(a1, x1, b1, y1)) { o2 = a1; p2 = x1; } else { o2 = b1; p2 = y1; }
        }
    } else {
        o0 = b0; p0 = y0;
        if (better(b1, y1, a0, x0)) {
            o1 = b1; p1 = y1;
            if (better(b2, y2, a0, x0)) { o2 = b2; p2 = y2; } else { o2 = a0; p2 = x0; }
        } else {
            o1 = a0; p1 = x0;
            if (better(a1, x1, b1, y1)) { o2 = a1; p2 = x1; } else { o2 = b1; p2 = y1; }
        }
    }
    a0 = o0; x0 = p0; a1 = o1; x1 = p1; a2 = o2; x2 = p2;
}

__global__ __launch_bounds__(BLK) void topk_softmax_kernel(const float* __restrict__ in,
                                                           float* __restrict__ out) {
    const int row = blockIdx.x;
    const float4* rin  = reinterpret_cast<const float4*>(in  + (size_t)row * ROWLEN);
    float4*       rout = reinterpret_cast<float4*>(      out + (size_t)row * ROWLEN);
    const int tid = threadIdx.x;

    float v0 = -INFINITY, v1 = -INFINITY, v2 = -INFINITY;
    int   i0 = 0x7fffffff, i1 = 0x7fffffff, i2 = 0x7fffffff;

    // coalesced: thread t loads float4 #(t + k*256), k=0..3  -> 16 elems/thread
    float4 d[4];
    #pragma unroll
    for (int k = 0; k < 4; ++k) d[k] = rin[tid + k * BLK];

    #pragma unroll
    for (int k = 0; k < 4; ++k) {
        const int e = 4 * (tid + k * BLK);
        ins3(d[k].x, e + 0, v0, i0, v1, i1, v2, i2);
        ins3(d[k].y, e + 1, v0, i0, v1, i1, v2, i2);
        ins3(d[k].z, e + 2, v0, i0, v1, i1, v2, i2);
        ins3(d[k].w, e + 3, v0, i0, v1, i1, v2, i2);
    }

    // 64-lane butterfly reduce of sorted triples
    #pragma unroll
    for (int off = 1; off < 64; off <<= 1) {
        float b0 = __shfl_xor(v0, off), b1 = __shfl_xor(v1, off), b2 = __shfl_xor(v2, off);
        int   y0 = __shfl_xor(i0, off), y1 = __shfl_xor(i1, off), y2 = __shfl_xor(i2, off);
        merge3(v0, i0, v1, i1, v2, i2, b0, y0, b1, y1, b2, y2);
    }

    // cross-wave merge (4 waves/block)
    __shared__ float sv[4][3];
    __shared__ int   si[4][3];
    __shared__ float sp[3];
    __shared__ int   sx[3];

    const int wave = tid >> 6;
    if ((tid & 63) == 0) {
        sv[wave][0] = v0; sv[wave][1] = v1; sv[wave][2] = v2;
        si[wave][0] = i0; si[wave][1] = i1; si[wave][2] = i2;
    }
    __syncthreads();
    if (tid == 0) {
        float a0 = sv[0][0], a1 = sv[0][1], a2 = sv[0][2];
        int   x0 = si[0][0], x1 = si[0][1], x2 = si[0][2];
        #pragma unroll
        for (int w = 1; w < 4; ++w)
            merge3(a0, x0, a1, x1, a2, x2,
                   sv[w][0], si[w][0], sv[w][1], si[w][1], sv[w][2], si[w][2]);
        // softmax over {a0,a1,a2}; all masked entries underflow to exactly 0 in fp32
        const float m  = a0;
        const float e0 = expf(a0 - m), e1 = expf(a1 - m), e2 = expf(a2 - m);
        const float inv = 1.0f / (e0 + e1 + e2);
        sp[0] = e0 * inv; sp[1] = e1 * inv; sp[2] = e2 * inv;
        sx[0] = x0; sx[1] = x1; sx[2] = x2;
    }
    __syncthreads();
    const float p0 = sp[0], p1 = sp[1], p2 = sp[2];
    const int   t0 = sx[0], t1 = sx[1], t2 = sx[2];

    // write: zeros except the 3 winners, branchless select, coalesced float4
    #pragma unroll
    for (int k = 0; k < 4; ++k) {
        const int e = 4 * (tid + k * BLK);
        float4 o;
        o.x = (e + 0 == t0) ? p0 : (e + 0 == t1) ? p1 : (e + 0 == t2) ? p2 : 0.0f;
        o.y = (e + 1 == t0) ? p0 : (e + 1 == t1) ? p1 : (e + 1 == t2) ? p2 : 0.0f;
        o.z = (e + 2 == t0) ? p0 : (e + 2 == t1) ? p1 : (e + 2 == t2) ? p2 : 0.0f;
        o.w = (e + 3 == t0) ? p0 : (e + 3 == t1) ? p1 : (e + 3 == t2) ? p2 : 0.0f;
        rout[tid + k * BLK] = o;
    }
}

extern "C" void kernel_launch(void* const* d_in, const int* in_sizes, int n_in,
                              void* d_out, int out_size, void* d_ws, size_t ws_size,
                              hipStream_t stream) {
    const float* in  = (const float*)d_in[0];
    float*       out = (float*)d_out;
    const int rows = in_sizes[0] / ROWLEN;   // 8*2048 = 16384
    topk_softmax_kernel<<<rows, BLK, 0, stream>>>(in, out);
}

// Round 2
// 321.877 us; speedup vs baseline: 1.1834x; 1.1834x over previous
//
#include <hip/hip_runtime.h>
#include <math.h>

#define ROWLEN 4096
#define BLK 256

__device__ __forceinline__ float med3f(float a, float b, float c) {
    return __builtin_amdgcn_fmed3f(a, b, c);
}
__device__ __forceinline__ float max3f(float a, float b, float c) {
    return fmaxf(fmaxf(a, b), c);   // clang fuses to v_max3_f32
}
__device__ __forceinline__ float min3f(float a, float b, float c) {
    return fminf(fminf(a, b), c);   // clang fuses to v_min3_f32
}

// branchless insert of v into sorted-descending triple (t0>=t1>=t2)
__device__ __forceinline__ void ins(float v, float& t0, float& t1, float& t2) {
    float n0 = fmaxf(t0, v);
    float n1 = med3f(t0, t1, v);
    float n2 = fmaxf(t2, fminf(t1, v));   // min3(t0,t1,v) == min(t1,v) since t0>=t1
    t0 = n0; t1 = n1; t2 = n2;
}

// branchless merge: (a0,a1,a2) <- top-3 of union of two sorted triples
__device__ __forceinline__ void mrg(float& a0, float& a1, float& a2,
                                    float b0, float b1, float b2) {
    float M  = fmaxf(a1, b1);
    float s  = fminf(a0, b0);
    float o0 = fmaxf(a0, b0);
    float o1 = med3f(a0, b0, M);
    float o2 = max3f(fminf(M, s), a2, b2);
    a0 = o0; a1 = o1; a2 = o2;
}

// exact ordering for the rare-tie fallback (matches jax.lax.top_k)
__device__ __forceinline__ bool better(float v, int i, float w, int j) {
    return (v > w) || (v == w && i < j);
}

__global__ __launch_bounds__(BLK) void topk_softmax_kernel(const float* __restrict__ in,
                                                           float* __restrict__ out) {
    const int row = blockIdx.x;
    const float4* rin  = reinterpret_cast<const float4*>(in  + (size_t)row * ROWLEN);
    float4*       rout = reinterpret_cast<float4*>(      out + (size_t)row * ROWLEN);
    const int tid = threadIdx.x;

    // coalesced: thread t loads float4 #(t + k*256)  -> 16 elems/thread
    float4 d0 = rin[tid];
    float4 d1 = rin[tid + BLK];
    float4 d2 = rin[tid + 2 * BLK];
    float4 d3 = rin[tid + 3 * BLK];

    // per-group sort3 + 1 insert (branchless, 4 independent chains)
    float g00 = max3f(d0.x, d0.y, d0.z), g01 = med3f(d0.x, d0.y, d0.z), g02 = min3f(d0.x, d0.y, d0.z);
    float g10 = max3f(d1.x, d1.y, d1.z), g11 = med3f(d1.x, d1.y, d1.z), g12 = min3f(d1.x, d1.y, d1.z);
    float g20 = max3f(d2.x, d2.y, d2.z), g21 = med3f(d2.x, d2.y, d2.z), g22 = min3f(d2.x, d2.y, d2.z);
    float g30 = max3f(d3.x, d3.y, d3.z), g31 = med3f(d3.x, d3.y, d3.z), g32 = min3f(d3.x, d3.y, d3.z);
    ins(d0.w, g00, g01, g02);
    ins(d1.w, g10, g11, g12);
    ins(d2.w, g20, g21, g22);
    ins(d3.w, g30, g31, g32);
    mrg(g00, g01, g02, g10, g11, g12);
    mrg(g20, g21, g22, g30, g31, g32);
    mrg(g00, g01, g02, g20, g21, g22);

    // 64-lane butterfly reduce of sorted value triples (3 shuffles/step)
    #pragma unroll
    for (int off = 1; off < 64; off <<= 1) {
        float b0 = __shfl_xor(g00, off);
        float b1 = __shfl_xor(g01, off);
        float b2 = __shfl_xor(g02, off);
        mrg(g00, g01, g02, b0, b1, b2);
    }

    __shared__ float sv[4][3];
    __shared__ int   s_cnt;
    __shared__ int   f_idx[3];
    __shared__ float f_p[3];

    if (tid == 0) s_cnt = 0;
    const int wave = tid >> 6;
    if ((tid & 63) == 0) { sv[wave][0] = g00; sv[wave][1] = g01; sv[wave][2] = g02; }
    __syncthreads();

    // every thread merges the 4 wave triples (broadcast LDS reads, no conflicts)
    float a0 = sv[0][0], a1 = sv[0][1], a2 = sv[0][2];
    mrg(a0, a1, a2, sv[1][0], sv[1][1], sv[1][2]);
    mrg(a0, a1, a2, sv[2][0], sv[2][1], sv[2][2]);
    mrg(a0, a1, a2, sv[3][0], sv[3][1], sv[3][2]);

    // exact row-wide count of elements >= a2 (detects ties at the rank-3 boundary)
    int c = 0;
    c += (d0.x >= a2) + (d0.y >= a2) + (d0.z >= a2) + (d0.w >= a2);
    c += (d1.x >= a2) + (d1.y >= a2) + (d1.z >= a2) + (d1.w >= a2);
    c += (d2.x >= a2) + (d2.y >= a2) + (d2.z >= a2) + (d2.w >= a2);
    c += (d3.x >= a2) + (d3.y >= a2) + (d3.z >= a2) + (d3.w >= a2);
    #pragma unroll
    for (int off = 1; off < 64; off <<= 1) c += __shfl_xor(c, off);
    if ((tid & 63) == 0) atomicAdd(&s_cnt, c);
    __syncthreads();

    if (s_cnt == 3) {
        // fast path: winners are exactly {a0,a1,a2}; probs need only 2 exps/thread
        const float e1   = __expf(a1 - a0);
        const float e2   = __expf(a2 - a0);
        const float invZ = 1.0f / (1.0f + e1 + e2);
        const float p0 = invZ, p1 = e1 * invZ, p2 = e2 * invZ;

        #pragma unroll
        for (int k = 0; k < 4; ++k) {
            const float4 v = (k == 0) ? d0 : (k == 1) ? d1 : (k == 2) ? d2 : d3;
            float4 o;
            o.x = (v.x < a2) ? 0.0f : (v.x < a1) ? p2 : (v.x < a0) ? p1 : p0;
            o.y = (v.y < a2) ? 0.0f : (v.y < a1) ? p2 : (v.y < a0) ? p1 : p0;
            o.z = (v.z < a2) ? 0.0f : (v.z < a1) ? p2 : (v.z < a0) ? p1 : p0;
            o.w = (v.w < a2) ? 0.0f : (v.w < a1) ? p2 : (v.w < a0) ? p1 : p0;
            rout[tid + k * BLK] = o;
        }
    } else {
        // rare exact fallback (block-uniform branch): tie at the rank-3 boundary.
        // thread 0 re-scans the row sequentially with index tie-break.
        if (tid == 0) {
            const float* r = in + (size_t)row * ROWLEN;
            float v0 = -INFINITY, v1 = -INFINITY, v2 = -INFINITY;
            int   i0 = 0x7fffffff, i1 = 0x7fffffff, i2 = 0x7fffffff;
            for (int j = 0; j < ROWLEN; ++j) {
                float v = r[j];
                if (better(v, j, v2, i2)) {
                    if (better(v, j, v1, i1)) {
                        v2 = v1; i2 = i1;
                        if (better(v, j, v0, i0)) { v1 = v0; i1 = i0; v0 = v; i0 = j; }
                        else                      { v1 = v;  i1 = j; }
                    } else { v2 = v; i2 = j; }
                }
            }
            const float e1 = __expf(v1 - v0), e2 = __expf(v2 - v0);
            const float invZ = 1.0f / (1.0f + e1 + e2);
            f_p[0] = invZ; f_p[1] = e1 * invZ; f_p[2] = e2 * invZ;
            f_idx[0] = i0; f_idx[1] = i1; f_idx[2] = i2;
        }
        __syncthreads();
        const float p0 = f_p[0], p1 = f_p[1], p2 = f_p[2];
        const int   t0 = f_idx[0], t1 = f_idx[1], t2 = f_idx[2];
        #pragma unroll
        for (int k = 0; k < 4; ++k) {
            const int e = 4 * (tid + k * BLK);
            float4 o;
            o.x = (e + 0 == t0) ? p0 : (e + 0 == t1) ? p1 : (e + 0 == t2) ? p2 : 0.0f;
            o.y = (e + 1 == t0) ? p0 : (e + 1 == t1) ? p1 : (e + 1 == t2) ? p2 : 0.0f;
            o.z = (e + 2 == t0) ? p0 : (e + 2 == t1) ? p1 : (e + 2 == t2) ? p2 : 0.0f;
            o.w = (e + 3 == t0) ? p0 : (e + 3 == t1) ? p1 : (e + 3 == t2) ? p2 : 0.0f;
            rout[tid + k * BLK] = o;
        }
    }
}

extern "C" void kernel_launch(void* const* d_in, const int* in_sizes, int n_in,
                              void* d_out, int out_size, void* d_ws, size_t ws_size,
                              hipStream_t stream) {
    const float* in  = (const float*)d_in[0];
    float*       out = (float*)d_out;
    const int rows = in_sizes[0] / ROWLEN;   // 8*2048 = 16384
    topk_softmax_kernel<<<rows, BLK, 0, stream>>>(in, out);
}